// Round 1
// baseline (306.749 us; speedup 1.0000x reference)
//
#include <hip/hip_runtime.h>
#include <math.h>

// RetNetRelPosDeform2D: B=8,H=8,N1=N2=32,slen=1024,D=64
// Outputs (fp32, flat-concatenated):
//   sin_q [8,8,1024,64]  @ 0
//   cos_q [8,8,1024,64]  @ 4194304
//   sin_k [1024,64]      @ 8388608
//   cos_k [1024,64]      @ 8454144
//   mask  [8,8,1024,1024]@ 8519680
#define OFF_COSQ  4194304
#define OFF_SINK  8388608
#define OFF_COSK  8454144
#define OFF_MASK  8519680
#define NROWS     65536   // B*H*slen

__global__ __launch_bounds__(256) void retnet_fused_kernel(
    const float* __restrict__ offsets,   // [B,H,32,32,2]
    const float* __restrict__ angle,     // [64]
    const float* __restrict__ decay,     // [8]
    float* __restrict__ out)
{
    const int wave = blockIdx.x * 4 + (threadIdx.x >> 6); // one wave per query row
    const int lane = threadIdx.x & 63;
    if (wave >= NROWS) return;

    const int bh = wave >> 10;      // b*8+h
    const int s  = wave & 1023;     // i*32+j
    const int h  = bh & 7;
    const int i  = s >> 5;
    const int j  = s & 31;

    const float off0 = offsets[(wave << 1) + 0];
    const float off1 = offsets[(wave << 1) + 1];
    const float i1q  = (float)i + off0;     // deformed row index
    const float i2q  = (float)j + off1;     // deformed col index
    const float dec  = decay[h];            // negative
    const float ang  = angle[lane];

    // ---- sin_q / cos_q (lane l handles dim d=l) ----
    {
        float sq, cq;
        __sincosf((i1q + i2q) * ang, &sq, &cq);
        out[(size_t)wave * 64 + lane] = sq;
        out[OFF_COSQ + (size_t)wave * 64 + lane] = cq;
    }

    // ---- sin_k / cos_k: only the first 1024 rows (bh==0) emit them ----
    if (bh == 0) {
        float sk, ck;
        __sincosf((float)(i + j) * ang, &sk, &ck);
        out[OFF_SINK + (size_t)s * 64 + lane] = sk;
        out[OFF_COSK + (size_t)s * 64 + lane] = ck;
    }

    // ---- mask row: exp(dec*(|i1q-ii|+|i2q-jj|)) / sqrt(sum1*sum2) ----
    // Distributed exponentials for the two 32-element factors:
    float v;
    if (lane < 32) v = __expf(dec * fabsf(i1q - (float)lane));
    else           v = __expf(dec * fabsf(i2q - (float)(lane - 32)));

    // Butterfly reduce within each 32-lane half (xor masks <= 16 never cross bit 5)
    float sum = v;
    #pragma unroll
    for (int m = 16; m >= 1; m >>= 1) sum += __shfl_xor(sum, m, 64);
    const float sum1 = __shfl(sum, 0, 64);    // sum over e1
    const float sum2 = __shfl(sum, 32, 64);   // sum over e2
    const float invnorm = rsqrtf(sum1 * sum2);

    // Each lane writes 4 float4s per row, fully coalesced:
    // float4 index f = k*64 + lane -> element e0 = 4*f;
    //   ii = e0>>5 = k*8 + (lane>>3), jj = e0&31 = (lane&7)*4 + c
    const int jj0 = (lane & 7) * 4;
    float e2a[4];
    #pragma unroll
    for (int c = 0; c < 4; ++c)
        e2a[c] = __expf(dec * fabsf(i2q - (float)(jj0 + c))) * invnorm;

    float4* mrow = (float4*)(out + OFF_MASK + (size_t)wave * 1024);
    #pragma unroll
    for (int k = 0; k < 4; ++k) {
        const int ii = k * 8 + (lane >> 3);
        const float e1 = __expf(dec * fabsf(i1q - (float)ii));
        float4 r;
        r.x = e1 * e2a[0];
        r.y = e1 * e2a[1];
        r.z = e1 * e2a[2];
        r.w = e1 * e2a[3];
        mrow[k * 64 + lane] = r;
    }
}

extern "C" void kernel_launch(void* const* d_in, const int* in_sizes, int n_in,
                              void* d_out, int out_size, void* d_ws, size_t ws_size,
                              hipStream_t stream) {
    // inputs: [0]=slen (int, unused), [1]=offsets fp32 [8,8,32,32,2],
    //         [2]=angle fp32 [64], [3]=decay fp32 [8]
    const float* offsets = (const float*)d_in[1];
    const float* angle   = (const float*)d_in[2];
    const float* decay   = (const float*)d_in[3];
    float* out = (float*)d_out;

    const int blocks = NROWS / 4;  // 4 waves (rows) per 256-thread block
    retnet_fused_kernel<<<blocks, 256, 0, stream>>>(offsets, angle, decay, out);
}

// Round 3
// 300.283 us; speedup vs baseline: 1.0215x; 1.0215x over previous
//
#include <hip/hip_runtime.h>
#include <math.h>

// RetNetRelPosDeform2D: B=8,H=8,N1=N2=32,slen=1024,D=64
// Outputs (fp32, flat-concatenated):
//   sin_q [8,8,1024,64]  @ 0
//   cos_q [8,8,1024,64]  @ 4194304
//   sin_k [1024,64]      @ 8388608
//   cos_k [1024,64]      @ 8454144
//   mask  [8,8,1024,1024]@ 8519680
#define OFF_COSQ  4194304
#define OFF_SINK  8388608
#define OFF_COSK  8454144
#define OFF_MASK  8519680
#define NROWS     65536   // B*H*slen

typedef float floatx4 __attribute__((ext_vector_type(4)));  // native vector: OK for nontemporal builtin

__global__ __launch_bounds__(256) void retnet_fused_kernel(
    const float* __restrict__ offsets,   // [B,H,32,32,2]
    const float* __restrict__ angle,     // [64]
    const float* __restrict__ decay,     // [8]
    float* __restrict__ out)
{
    const int wave = blockIdx.x * 4 + (threadIdx.x >> 6); // one wave per query row
    const int lane = threadIdx.x & 63;
    if (wave >= NROWS) return;

    const int bh = wave >> 10;      // b*8+h
    const int s  = wave & 1023;     // i*32+j
    const int h  = bh & 7;
    const int i  = s >> 5;
    const int j  = s & 31;

    const float off0 = offsets[(wave << 1) + 0];
    const float off1 = offsets[(wave << 1) + 1];
    const float i1q  = (float)i + off0;     // deformed row index
    const float i2q  = (float)j + off1;     // deformed col index
    const float dec  = decay[h];            // negative
    const float ang  = angle[lane];

    // ---- sin_q / cos_q (lane l handles dim d=l) ----
    {
        float sq, cq;
        __sincosf((i1q + i2q) * ang, &sq, &cq);
        __builtin_nontemporal_store(sq, &out[(size_t)wave * 64 + lane]);
        __builtin_nontemporal_store(cq, &out[OFF_COSQ + (size_t)wave * 64 + lane]);
    }

    // ---- sin_k / cos_k: only the first 1024 rows (bh==0) emit them ----
    if (bh == 0) {
        float sk, ck;
        __sincosf((float)(i + j) * ang, &sk, &ck);
        __builtin_nontemporal_store(sk, &out[OFF_SINK + (size_t)s * 64 + lane]);
        __builtin_nontemporal_store(ck, &out[OFF_COSK + (size_t)s * 64 + lane]);
    }

    // ---- mask row: exp(dec*(|i1q-ii|+|i2q-jj|)) / sqrt(sum1*sum2) ----
    // Distributed exponentials for the two 32-element factors:
    float v;
    if (lane < 32) v = __expf(dec * fabsf(i1q - (float)lane));
    else           v = __expf(dec * fabsf(i2q - (float)(lane - 32)));

    // Butterfly reduce within each 32-lane half (xor masks <= 16 never cross bit 5)
    float sum = v;
    #pragma unroll
    for (int m = 16; m >= 1; m >>= 1) sum += __shfl_xor(sum, m, 64);
    const float sum1 = __shfl(sum, 0, 64);    // sum over e1
    const float sum2 = __shfl(sum, 32, 64);   // sum over e2
    const float invnorm = rsqrtf(sum1 * sum2);

    // Each lane writes 4 float4s per row, fully coalesced:
    // float4 index f = k*64 + lane -> element e0 = 4*f;
    //   ii = e0>>5 = k*8 + (lane>>3), jj = e0&31 = (lane&7)*4 + c
    const int jj0 = (lane & 7) * 4;
    float e2a[4];
    #pragma unroll
    for (int c = 0; c < 4; ++c)
        e2a[c] = __expf(dec * fabsf(i2q - (float)(jj0 + c))) * invnorm;

    floatx4* mrow = (floatx4*)(out + OFF_MASK + (size_t)wave * 1024);
    #pragma unroll
    for (int k = 0; k < 4; ++k) {
        const int ii = k * 8 + (lane >> 3);
        const float e1 = __expf(dec * fabsf(i1q - (float)ii));
        floatx4 r;
        r.x = e1 * e2a[0];
        r.y = e1 * e2a[1];
        r.z = e1 * e2a[2];
        r.w = e1 * e2a[3];
        __builtin_nontemporal_store(r, &mrow[k * 64 + lane]);
    }
}

extern "C" void kernel_launch(void* const* d_in, const int* in_sizes, int n_in,
                              void* d_out, int out_size, void* d_ws, size_t ws_size,
                              hipStream_t stream) {
    // inputs: [0]=slen (int, unused), [1]=offsets fp32 [8,8,32,32,2],
    //         [2]=angle fp32 [64], [3]=decay fp32 [8]
    const float* offsets = (const float*)d_in[1];
    const float* angle   = (const float*)d_in[2];
    const float* decay   = (const float*)d_in[3];
    float* out = (float*)d_out;

    const int blocks = NROWS / 4;  // 4 waves (rows) per 256-thread block
    retnet_fused_kernel<<<blocks, 256, 0, stream>>>(offsets, angle, decay, out);
}